// Round 2
// baseline (2248.990 us; speedup 1.0000x reference)
//
#include <hip/hip_runtime.h>
#include <hip/hip_bf16.h>
#include <math.h>

#define BB 4
#define SS 2048
#define DM 1024
#define NH 16
#define DH 64
#define MROWS (BB*SS)

// C[m][n] = sum_k A[m][k] * W[n][k].  A:[MROWS,1024] row-major, W:[1024,1024] row-major.
// 128x128 tile, BK=16, 256 threads, 8x8 micro-tile.
// MODE 0: write out[b][h][s][dh] (head-major for attention). MODE 1: out[m][n] + bias.
template<int MODE>
__global__ __launch_bounds__(256) void gemm_xwt(const float* __restrict__ A,
                                                const float* __restrict__ W,
                                                float* __restrict__ out,
                                                const float* __restrict__ bias) {
    __shared__ float Ast[16][132];  // [k][m-row], transposed; stride 132 keeps float4 alignment
    __shared__ float Bst[16][132];  // [k][n-row]
    const int t  = threadIdx.x;
    const int ty = t >> 4, tx = t & 15;
    const int m0 = blockIdx.x * 128;
    const int n0 = blockIdx.y * 128;
    float c[8][8] = {};
    for (int k0 = 0; k0 < DM; k0 += 16) {
        #pragma unroll
        for (int r = 0; r < 2; ++r) {
            const int slot = t + 256 * r;
            const int row  = slot >> 2;          // 0..127
            const int k4   = (slot & 3) * 4;     // 0,4,8,12
            const float4 av = *(const float4*)(A + (size_t)(m0 + row) * DM + k0 + k4);
            Ast[k4+0][row] = av.x; Ast[k4+1][row] = av.y;
            Ast[k4+2][row] = av.z; Ast[k4+3][row] = av.w;
            const float4 bv = *(const float4*)(W + (size_t)(n0 + row) * DM + k0 + k4);
            Bst[k4+0][row] = bv.x; Bst[k4+1][row] = bv.y;
            Bst[k4+2][row] = bv.z; Bst[k4+3][row] = bv.w;
        }
        __syncthreads();
        #pragma unroll
        for (int k = 0; k < 16; ++k) {
            const float4 a0 = *(const float4*)&Ast[k][ty * 4];
            const float4 a1 = *(const float4*)&Ast[k][64 + ty * 4];
            const float4 b0 = *(const float4*)&Bst[k][tx * 4];
            const float4 b1 = *(const float4*)&Bst[k][64 + tx * 4];
            const float ar[8] = {a0.x, a0.y, a0.z, a0.w, a1.x, a1.y, a1.z, a1.w};
            const float br[8] = {b0.x, b0.y, b0.z, b0.w, b1.x, b1.y, b1.z, b1.w};
            #pragma unroll
            for (int i = 0; i < 8; ++i)
                #pragma unroll
                for (int j = 0; j < 8; ++j)
                    c[i][j] = fmaf(ar[i], br[j], c[i][j]);
        }
        __syncthreads();
    }
    #pragma unroll
    for (int hm = 0; hm < 2; ++hm) {
        #pragma unroll
        for (int i = 0; i < 4; ++i) {
            const int m = m0 + hm * 64 + ty * 4 + i;
            #pragma unroll
            for (int hn = 0; hn < 2; ++hn) {
                const int ci = hm * 4 + i;
                float4 v = {c[ci][hn*4+0], c[ci][hn*4+1], c[ci][hn*4+2], c[ci][hn*4+3]};
                const int col = n0 + hn * 64 + tx * 4;
                if (MODE == 0) {
                    const int b = m >> 11, s = m & 2047;
                    const int h = col >> 6, dh = col & 63;
                    *(float4*)(out + ((size_t)(b * NH + h) * SS + s) * DH + dh) = v;
                } else {
                    const float4 bi = *(const float4*)(bias + col);
                    v.x += bi.x; v.y += bi.y; v.z += bi.z; v.w += bi.w;
                    *(float4*)(out + (size_t)m * DM + col) = v;
                }
            }
        }
    }
}

// Flash attention fp32: Q,K,V in [B*H][S][64]; AO in [B][S][1024].
__global__ __launch_bounds__(256) void attn_fwd(const float* __restrict__ Qp,
                                                const float* __restrict__ Kp,
                                                const float* __restrict__ Vp,
                                                float* __restrict__ AO) {
    __shared__ float Qs[64][68];  // [qrow][d]
    __shared__ float Ks[64][68];  // [krow][d]
    __shared__ float Vs[64][68];  // [krow][d]
    __shared__ float Ps[64][68];  // [qrow][kcol]
    const int t  = threadIdx.x;
    const int ty = t >> 4, tx = t & 15;
    const int bh = blockIdx.y;
    const int q0 = blockIdx.x * 64;
    const float* Qb = Qp + (size_t)bh * SS * DH;
    const float* Kb = Kp + (size_t)bh * SS * DH;
    const float* Vb = Vp + (size_t)bh * SS * DH;

    #pragma unroll
    for (int r = 0; r < 4; ++r) {
        const int slot = t + 256 * r;
        const int row  = slot >> 4;
        const int d4   = (slot & 15) * 4;
        float4 v = *(const float4*)(Qb + (size_t)(q0 + row) * DH + d4);
        v.x *= 0.125f; v.y *= 0.125f; v.z *= 0.125f; v.w *= 0.125f;  // 1/sqrt(64)
        *(float4*)&Qs[row][d4] = v;
    }

    float o[4][4] = {};
    float mrow[4] = {-INFINITY, -INFINITY, -INFINITY, -INFINITY};
    float lrow[4] = {};

    for (int kt = 0; kt < SS / 64; ++kt) {
        __syncthreads();  // protect Ks/Vs (and Qs on iter 0) from prior readers
        #pragma unroll
        for (int r = 0; r < 4; ++r) {
            const int slot = t + 256 * r;
            const int row  = slot >> 4;
            const int d4   = (slot & 15) * 4;
            *(float4*)&Ks[row][d4] = *(const float4*)(Kb + (size_t)(kt * 64 + row) * DH + d4);
            *(float4*)&Vs[row][d4] = *(const float4*)(Vb + (size_t)(kt * 64 + row) * DH + d4);
        }
        __syncthreads();

        // S = Q K^T : rows ty*4+i, cols tx+16*j
        float s[4][4] = {};
        #pragma unroll
        for (int d4 = 0; d4 < 64; d4 += 4) {
            float4 q4[4], k4[4];
            #pragma unroll
            for (int i = 0; i < 4; ++i) q4[i] = *(const float4*)&Qs[ty * 4 + i][d4];
            #pragma unroll
            for (int j = 0; j < 4; ++j) k4[j] = *(const float4*)&Ks[tx + 16 * j][d4];
            #pragma unroll
            for (int i = 0; i < 4; ++i)
                #pragma unroll
                for (int j = 0; j < 4; ++j) {
                    s[i][j] = fmaf(q4[i].x, k4[j].x, s[i][j]);
                    s[i][j] = fmaf(q4[i].y, k4[j].y, s[i][j]);
                    s[i][j] = fmaf(q4[i].z, k4[j].z, s[i][j]);
                    s[i][j] = fmaf(q4[i].w, k4[j].w, s[i][j]);
                }
        }

        // online softmax; P row is wave-local (same ty group = same wave)
        #pragma unroll
        for (int i = 0; i < 4; ++i) {
            float mx = fmaxf(fmaxf(s[i][0], s[i][1]), fmaxf(s[i][2], s[i][3]));
            #pragma unroll
            for (int m = 1; m < 16; m <<= 1) mx = fmaxf(mx, __shfl_xor(mx, m, 64));
            const float newm  = fmaxf(mrow[i], mx);
            const float scale = __expf(mrow[i] - newm);
            mrow[i] = newm;
            float rs = 0.f;
            #pragma unroll
            for (int j = 0; j < 4; ++j) {
                const float p = __expf(s[i][j] - newm);
                rs += p;
                Ps[ty * 4 + i][tx + 16 * j] = p;
            }
            #pragma unroll
            for (int m = 1; m < 16; m <<= 1) rs += __shfl_xor(rs, m, 64);
            lrow[i] = lrow[i] * scale + rs;
            #pragma unroll
            for (int j = 0; j < 4; ++j) o[i][j] *= scale;
        }

        // O += P V : rows ty*4+i, d-cols tx*4+di
        #pragma unroll
        for (int j4 = 0; j4 < 64; j4 += 4) {
            float4 p4[4], v4[4];
            #pragma unroll
            for (int i = 0; i < 4; ++i) p4[i] = *(const float4*)&Ps[ty * 4 + i][j4];
            #pragma unroll
            for (int jj = 0; jj < 4; ++jj) v4[jj] = *(const float4*)&Vs[j4 + jj][tx * 4];
            #pragma unroll
            for (int i = 0; i < 4; ++i) {
                const float pr[4] = {p4[i].x, p4[i].y, p4[i].z, p4[i].w};
                #pragma unroll
                for (int jj = 0; jj < 4; ++jj) {
                    o[i][0] = fmaf(pr[jj], v4[jj].x, o[i][0]);
                    o[i][1] = fmaf(pr[jj], v4[jj].y, o[i][1]);
                    o[i][2] = fmaf(pr[jj], v4[jj].z, o[i][2]);
                    o[i][3] = fmaf(pr[jj], v4[jj].w, o[i][3]);
                }
            }
        }
    }

    const int b = bh >> 4, h = bh & 15;
    #pragma unroll
    for (int i = 0; i < 4; ++i) {
        const float inv = 1.f / lrow[i];
        const int srow  = q0 + ty * 4 + i;
        float4 v = {o[i][0] * inv, o[i][1] * inv, o[i][2] * inv, o[i][3] * inv};
        *(float4*)(AO + ((size_t)(b * SS + srow) * DM) + h * DH + tx * 4) = v;
    }
}

extern "C" void kernel_launch(void* const* d_in, const int* in_sizes, int n_in,
                              void* d_out, int out_size, void* d_ws, size_t ws_size,
                              hipStream_t stream) {
    const float* x  = (const float*)d_in[0];
    const float* Wq = (const float*)d_in[1];
    const float* Wk = (const float*)d_in[2];
    const float* Wv = (const float*)d_in[3];
    const float* Wo = (const float*)d_in[4];
    const float* bo = (const float*)d_in[5];
    float* out = (float*)d_out;

    float* Q  = (float*)d_ws;                       // [B*H][S][64]
    float* K  = Q + (size_t)MROWS * DM;
    float* V  = K + (size_t)MROWS * DM;
    float* AO = V + (size_t)MROWS * DM;             // [B][S][1024]

    const dim3 blk(256);
    const dim3 gg(MROWS / 128, DM / 128);
    gemm_xwt<0><<<gg, blk, 0, stream>>>(x, Wq, Q, nullptr);
    gemm_xwt<0><<<gg, blk, 0, stream>>>(x, Wk, K, nullptr);
    gemm_xwt<0><<<gg, blk, 0, stream>>>(x, Wv, V, nullptr);
    attn_fwd<<<dim3(SS / 64, BB * NH), blk, 0, stream>>>(Q, K, V, AO);
    gemm_xwt<1><<<gg, blk, 0, stream>>>(AO, Wo, out, bo);
}

// Round 3
// 1112.158 us; speedup vs baseline: 2.0222x; 2.0222x over previous
//
#include <hip/hip_runtime.h>
#include <hip/hip_bf16.h>
#include <math.h>

#define BB 4
#define SS 2048
#define DM 1024
#define NH 16
#define DH 64
#define MROWS (BB*SS)

typedef __attribute__((ext_vector_type(8))) short bf16x8;
typedef __attribute__((ext_vector_type(4))) float f32x4;
typedef __attribute__((ext_vector_type(8))) unsigned short u16x8;

// C[m][n] = sum_k A[m][k] * W[n][k].  128x128 tile, BK=16, 256 threads, 8x8 micro-tile.
// MODE 0: write bf16 head-major out[bh][s][64], scaled by oscale. MODE 1: fp32 out[m][n] + bias.
template<int MODE>
__global__ __launch_bounds__(256) void gemm_xwt(const float* __restrict__ A,
                                                const float* __restrict__ W,
                                                void* __restrict__ outp,
                                                const float* __restrict__ bias,
                                                float oscale) {
    __shared__ float Ast[16][132];
    __shared__ float Bst[16][132];
    const int t  = threadIdx.x;
    const int ty = t >> 4, tx = t & 15;
    const int m0 = blockIdx.x * 128;
    const int n0 = blockIdx.y * 128;
    float c[8][8] = {};
    for (int k0 = 0; k0 < DM; k0 += 16) {
        #pragma unroll
        for (int r = 0; r < 2; ++r) {
            const int slot = t + 256 * r;
            const int row  = slot >> 2;
            const int k4   = (slot & 3) * 4;
            const float4 av = *(const float4*)(A + (size_t)(m0 + row) * DM + k0 + k4);
            Ast[k4+0][row] = av.x; Ast[k4+1][row] = av.y;
            Ast[k4+2][row] = av.z; Ast[k4+3][row] = av.w;
            const float4 bv = *(const float4*)(W + (size_t)(n0 + row) * DM + k0 + k4);
            Bst[k4+0][row] = bv.x; Bst[k4+1][row] = bv.y;
            Bst[k4+2][row] = bv.z; Bst[k4+3][row] = bv.w;
        }
        __syncthreads();
        #pragma unroll
        for (int k = 0; k < 16; ++k) {
            const float4 a0 = *(const float4*)&Ast[k][ty * 4];
            const float4 a1 = *(const float4*)&Ast[k][64 + ty * 4];
            const float4 b0 = *(const float4*)&Bst[k][tx * 4];
            const float4 b1 = *(const float4*)&Bst[k][64 + tx * 4];
            const float ar[8] = {a0.x, a0.y, a0.z, a0.w, a1.x, a1.y, a1.z, a1.w};
            const float br[8] = {b0.x, b0.y, b0.z, b0.w, b1.x, b1.y, b1.z, b1.w};
            #pragma unroll
            for (int i = 0; i < 8; ++i)
                #pragma unroll
                for (int j = 0; j < 8; ++j)
                    c[i][j] = fmaf(ar[i], br[j], c[i][j]);
        }
        __syncthreads();
    }
    #pragma unroll
    for (int hm = 0; hm < 2; ++hm) {
        #pragma unroll
        for (int i = 0; i < 4; ++i) {
            const int m = m0 + hm * 64 + ty * 4 + i;
            const int ci = hm * 4 + i;
            #pragma unroll
            for (int hn = 0; hn < 2; ++hn) {
                const int col = n0 + hn * 64 + tx * 4;
                if (MODE == 0) {
                    unsigned short* ob = (unsigned short*)outp;
                    const int b = m >> 11, s = m & 2047;
                    const int h = col >> 6, dh = col & 63;
                    unsigned short pk[4];
                    #pragma unroll
                    for (int j = 0; j < 4; ++j) {
                        __hip_bfloat16 bv = __float2bfloat16(c[ci][hn*4+j] * oscale);
                        pk[j] = *reinterpret_cast<unsigned short*>(&bv);
                    }
                    *reinterpret_cast<unsigned long long*>(ob + ((size_t)(b * NH + h) * SS + s) * 64 + dh)
                        = *reinterpret_cast<unsigned long long*>(pk);
                } else {
                    float* of = (float*)outp;
                    const float4 bi = *(const float4*)(bias + col);
                    float4 v = {c[ci][hn*4+0] + bi.x, c[ci][hn*4+1] + bi.y,
                                c[ci][hn*4+2] + bi.z, c[ci][hn*4+3] + bi.w};
                    *(float4*)(of + (size_t)m * DM + col) = v;
                }
            }
        }
    }
}

// Vb[bh][s][64] bf16 -> Vt[bh][64][S] bf16
__global__ __launch_bounds__(256) void transpose_v(const unsigned short* __restrict__ Vb,
                                                   unsigned short* __restrict__ Vt) {
    __shared__ unsigned short T[64][72];
    const int t  = threadIdx.x;
    const int bh = blockIdx.y;
    const int s0 = blockIdx.x * 64;
    #pragma unroll
    for (int r = 0; r < 2; ++r) {
        const int idx = t + 256 * r;
        const int row = idx >> 3;
        const int d8  = (idx & 7) * 8;
        *(u16x8*)&T[row][d8] = *(const u16x8*)(Vb + ((size_t)bh * SS + s0 + row) * 64 + d8);
    }
    __syncthreads();
    const int d  = t >> 2;
    const int sc = (t & 3) * 16;
    unsigned short tmp[16];
    #pragma unroll
    for (int i = 0; i < 16; ++i) tmp[i] = T[sc + i][d];
    unsigned short* dst = Vt + ((size_t)bh * 64 + d) * SS + s0 + sc;
    *(u16x8*)(dst)     = *(u16x8*)&tmp[0];
    *(u16x8*)(dst + 8) = *(u16x8*)&tmp[8];
}

// MFMA flash attention. Qb,Kb: [BH][S][64] bf16 (Q prescaled 1/8). Vt: [BH][64][S] bf16.
// AO: [B][S][1024] fp32. Block: 4 waves; wave w owns Q rows q0+w*16..+15. KV tile 64.
__global__ __launch_bounds__(256) void attn_mfma(const unsigned short* __restrict__ Qb,
                                                 const unsigned short* __restrict__ Kb,
                                                 const unsigned short* __restrict__ Vtp,
                                                 float* __restrict__ AO) {
    __shared__ unsigned short Ks[64*64];  // [key][dh], dh 8-groups XOR-swizzled by key&7
    __shared__ unsigned short Vs[64*64];  // [dh][key], key 8-groups XOR-swizzled by dh&7
    __shared__ unsigned short Ps[64*64];  // [qrow][key], key XOR-swizzled by qrow&7
    const int t    = threadIdx.x;
    const int lane = t & 63;
    const int w    = t >> 6;
    const int g    = lane >> 4;
    const int cc   = lane & 15;
    const int bh   = blockIdx.y;
    const int q0   = blockIdx.x * 64;

    // A-fragment of Q: row = lane%16, k = 8*(lane/16)+i, per 32-k step
    const unsigned short* Qw = Qb + ((size_t)bh * SS + q0 + w * 16 + cc) * 64;
    const bf16x8 qf0 = *(const bf16x8*)(Qw + 8 * g);
    const bf16x8 qf1 = *(const bf16x8*)(Qw + 32 + 8 * g);

    const unsigned short* Kbase = Kb  + (size_t)bh * SS * 64;
    const unsigned short* Vbase = Vtp + (size_t)bh * 64 * SS;

    const f32x4 zf = {0.f, 0.f, 0.f, 0.f};
    f32x4 oacc[4] = {zf, zf, zf, zf};
    float mrow[4] = {-INFINITY, -INFINITY, -INFINITY, -INFINITY};
    float lrow[4] = {0.f, 0.f, 0.f, 0.f};

    for (int kt = 0; kt < SS / 64; ++kt) {
        __syncthreads();
        #pragma unroll
        for (int r2 = 0; r2 < 2; ++r2) {
            const int idx = t + 256 * r2;
            const int row = idx >> 3;
            const int g8  = idx & 7;
            *(u16x8*)&Ks[row * 64 + ((g8 ^ (row & 7)) << 3)] =
                *(const u16x8*)(Kbase + ((size_t)(kt * 64 + row)) * 64 + g8 * 8);
            *(u16x8*)&Vs[row * 64 + ((g8 ^ (row & 7)) << 3)] =
                *(const u16x8*)(Vbase + (size_t)row * SS + kt * 64 + g8 * 8);
        }
        __syncthreads();

        // S = Q K^T : D row = 4*g+r, col = n*16+cc (m89 layout)
        f32x4 sacc[4] = {zf, zf, zf, zf};
        #pragma unroll
        for (int n = 0; n < 4; ++n) {
            const int key = n * 16 + cc;
            const bf16x8 kf0 = *(const bf16x8*)&Ks[key * 64 + ((g       ^ (key & 7)) << 3)];
            const bf16x8 kf1 = *(const bf16x8*)&Ks[key * 64 + (((4 + g) ^ (key & 7)) << 3)];
            sacc[n] = __builtin_amdgcn_mfma_f32_16x16x32_bf16(qf0, kf0, sacc[n], 0, 0, 0);
            sacc[n] = __builtin_amdgcn_mfma_f32_16x16x32_bf16(qf1, kf1, sacc[n], 0, 0, 0);
        }

        // online softmax: each lane owns rows 4g+r (replicated over 16-lane group), col cc of 4 tiles
        float p[4][4];
        float scl[4];
        #pragma unroll
        for (int r = 0; r < 4; ++r) {
            float mx = fmaxf(fmaxf(sacc[0][r], sacc[1][r]), fmaxf(sacc[2][r], sacc[3][r]));
            mx = fmaxf(mx, __shfl_xor(mx, 1));
            mx = fmaxf(mx, __shfl_xor(mx, 2));
            mx = fmaxf(mx, __shfl_xor(mx, 4));
            mx = fmaxf(mx, __shfl_xor(mx, 8));
            const float nm = fmaxf(mrow[r], mx);
            scl[r] = __expf(mrow[r] - nm);
            mrow[r] = nm;
            float rs = 0.f;
            #pragma unroll
            for (int n = 0; n < 4; ++n) {
                const float pv = __expf(sacc[n][r] - nm);
                p[n][r] = pv;
                rs += pv;
            }
            rs += __shfl_xor(rs, 1);
            rs += __shfl_xor(rs, 2);
            rs += __shfl_xor(rs, 4);
            rs += __shfl_xor(rs, 8);
            lrow[r] = lrow[r] * scl[r] + rs;
        }

        // P -> LDS bf16 (wave-private rows; no barrier needed)
        #pragma unroll
        for (int n = 0; n < 4; ++n)
            #pragma unroll
            for (int r = 0; r < 4; ++r) {
                const int qr  = w * 16 + g * 4 + r;
                const int key = n * 16 + cc;
                __hip_bfloat16 pb = __float2bfloat16(p[n][r]);
                Ps[qr * 64 + (key ^ ((qr & 7) << 3))] = *reinterpret_cast<unsigned short*>(&pb);
            }

        #pragma unroll
        for (int n = 0; n < 4; ++n) {
            oacc[n][0] *= scl[0]; oacc[n][1] *= scl[1];
            oacc[n][2] *= scl[2]; oacc[n][3] *= scl[3];
        }

        // O += P V
        const int qrow = w * 16 + cc;
        #pragma unroll
        for (int ks = 0; ks < 2; ++ks) {
            const bf16x8 pf = *(const bf16x8*)&Ps[qrow * 64 + (((ks * 4 + g) ^ (qrow & 7)) << 3)];
            #pragma unroll
            for (int n = 0; n < 4; ++n) {
                const int vrow = n * 16 + cc;
                const bf16x8 vf = *(const bf16x8*)&Vs[vrow * 64 + (((ks * 4 + g) ^ (vrow & 7)) << 3)];
                oacc[n] = __builtin_amdgcn_mfma_f32_16x16x32_bf16(pf, vf, oacc[n], 0, 0, 0);
            }
        }
    }

    const int b = bh >> 4, h = bh & 15;
    #pragma unroll
    for (int r = 0; r < 4; ++r) {
        const float inv  = 1.f / lrow[r];
        const int   srow = q0 + w * 16 + g * 4 + r;
        float* dst = AO + ((size_t)(b * SS + srow)) * DM + h * 64;
        dst[ 0 + cc] = oacc[0][r] * inv;
        dst[16 + cc] = oacc[1][r] * inv;
        dst[32 + cc] = oacc[2][r] * inv;
        dst[48 + cc] = oacc[3][r] * inv;
    }
}

extern "C" void kernel_launch(void* const* d_in, const int* in_sizes, int n_in,
                              void* d_out, int out_size, void* d_ws, size_t ws_size,
                              hipStream_t stream) {
    const float* x  = (const float*)d_in[0];
    const float* Wq = (const float*)d_in[1];
    const float* Wk = (const float*)d_in[2];
    const float* Wv = (const float*)d_in[3];
    const float* Wo = (const float*)d_in[4];
    const float* bo = (const float*)d_in[5];
    float* out = (float*)d_out;

    const size_t NEL = (size_t)BB * NH * SS * DH;   // 8.4M elements per tensor
    unsigned short* Qb  = (unsigned short*)d_ws;    // 16MB
    unsigned short* Kb  = Qb + NEL;                 // 16MB
    unsigned short* Vb  = Kb + NEL;                 // 16MB
    unsigned short* Vtp = Vb + NEL;                 // 16MB
    float*          AO  = (float*)(Vtp + NEL);      // 32MB

    const dim3 blk(256);
    const dim3 gg(MROWS / 128, DM / 128);
    gemm_xwt<0><<<gg, blk, 0, stream>>>(x, Wq, Qb, nullptr, 0.125f);
    gemm_xwt<0><<<gg, blk, 0, stream>>>(x, Wk, Kb, nullptr, 1.0f);
    gemm_xwt<0><<<gg, blk, 0, stream>>>(x, Wv, Vb, nullptr, 1.0f);
    transpose_v<<<dim3(SS / 64, BB * NH), blk, 0, stream>>>(Vb, Vtp);
    attn_mfma<<<dim3(SS / 64, BB * NH), blk, 0, stream>>>(Qb, Kb, Vtp, AO);
    gemm_xwt<1><<<gg, blk, 0, stream>>>(AO, Wo, (void*)out, bo, 1.0f);
}

// Round 9
// 397.629 us; speedup vs baseline: 5.6560x; 2.7970x over previous
//
#include <hip/hip_runtime.h>
#include <hip/hip_bf16.h>
#include <math.h>

#define BB 4
#define SS 2048
#define DM 1024
#define NH 16
#define DH 64
#define MROWS (BB*SS)

typedef __attribute__((ext_vector_type(8))) short bf16x8;
typedef __attribute__((ext_vector_type(4))) float f32x4;
typedef __attribute__((ext_vector_type(8))) unsigned short u16x8;

__device__ __forceinline__ unsigned short f2b(float f) {
    __hip_bfloat16 b = __float2bfloat16(f);
    return *reinterpret_cast<unsigned short*>(&b);
}

__device__ __forceinline__ void gload_lds16(const void* g, void* l) {
    __builtin_amdgcn_global_load_lds((const __attribute__((address_space(1))) unsigned int*)g,
                                     (__attribute__((address_space(3))) unsigned int*)l,
                                     16, 0, 0);
}

// ---------------- casts ----------------
__global__ __launch_bounds__(256) void cast_x_kernel(const float* __restrict__ in,
                                                     unsigned short* __restrict__ out) {
    const size_t i = ((size_t)blockIdx.x * 256 + threadIdx.x) * 8;
    const float4 a = *(const float4*)(in + i);
    const float4 b = *(const float4*)(in + i + 4);
    unsigned short pk[8] = {f2b(a.x), f2b(a.y), f2b(a.z), f2b(a.w),
                            f2b(b.x), f2b(b.y), f2b(b.z), f2b(b.w)};
    *(u16x8*)(out + i) = *(u16x8*)pk;
}

__global__ __launch_bounds__(256) void cast_w_kernel(const float* __restrict__ Wq,
                                                     const float* __restrict__ Wk,
                                                     const float* __restrict__ Wv,
                                                     const float* __restrict__ Wo,
                                                     unsigned short* __restrict__ out) {
    const float* src = (blockIdx.y == 0) ? Wq : (blockIdx.y == 1) ? Wk
                     : (blockIdx.y == 2) ? Wv : Wo;
    const size_t i = ((size_t)blockIdx.x * 256 + threadIdx.x) * 8;
    const float4 a = *(const float4*)(src + i);
    const float4 b = *(const float4*)(src + i + 4);
    unsigned short pk[8] = {f2b(a.x), f2b(a.y), f2b(a.z), f2b(a.w),
                            f2b(b.x), f2b(b.y), f2b(b.z), f2b(b.w)};
    *(u16x8*)(out + (size_t)blockIdx.y * DM * DM + i) = *(u16x8*)pk;
}

// ---------------- bf16 MFMA GEMM: C[m][n] = sum_k A[m][k] * W[n][k] ----------------
// 128x128 tile, BK=64, 4 waves (2x2), each wave 64x64 = 4x4 frags of 16x16x32.
// LDS: [row][8 x 16B-blocks], block j holds global k-block j^(row&7) (XOR swizzle,
// staged via pre-swizzled global source so global_load_lds dest stays lane-linear).
// MODE 0: out bf16 head-major [b,h,s,dh], z picks (W,out,scale). MODE 1: fp32 out[m][n]+bias.
template<int MODE>
__global__ __launch_bounds__(256) void gemm_mfma(const unsigned short* __restrict__ A,
                                                 const unsigned short* __restrict__ Wq,
                                                 const unsigned short* __restrict__ Wk,
                                                 const unsigned short* __restrict__ Wv,
                                                 unsigned short* __restrict__ Oq,
                                                 unsigned short* __restrict__ Ok,
                                                 unsigned short* __restrict__ Ov,
                                                 float* __restrict__ outf,
                                                 const float* __restrict__ bias) {
    __shared__ unsigned short As[128 * 64];
    __shared__ unsigned short Bs[128 * 64];
    const int t  = threadIdx.x;
    const int l  = t & 63;
    const int w  = t >> 6;
    const int g  = l >> 4;      // 0..3
    const int cc = l & 15;      // 0..15
    const int wr = w >> 1, wc = w & 1;
    const int m0 = blockIdx.x * 128;
    const int n0 = blockIdx.y * 128;

    const unsigned short* W;
    unsigned short* Ob = nullptr;
    float oscale = 1.f;
    if (MODE == 0) {
        const int z = blockIdx.z;
        W  = (z == 0) ? Wq : (z == 1) ? Wk : Wv;
        Ob = (z == 0) ? Oq : (z == 1) ? Ok : Ov;
        if (z == 0) oscale = 0.125f;
    } else {
        W = Wq;
    }

    const f32x4 zf = {0.f, 0.f, 0.f, 0.f};
    f32x4 acc[4][4] = {{zf,zf,zf,zf},{zf,zf,zf,zf},{zf,zf,zf,zf},{zf,zf,zf,zf}};

    for (int k0 = 0; k0 < DM; k0 += 64) {
        __syncthreads();   // previous tile's readers done
        #pragma unroll
        for (int i = 0; i < 4; ++i) {
            const int s   = i * 256 + t;      // lane-linear slot
            const int row = s >> 3;
            const int j   = s & 7;
            const int gb  = j ^ (row & 7);    // inverse-swizzled global k-block
            gload_lds16(A + (size_t)(m0 + row) * DM + k0 + gb * 8, &As[s * 8]);
            gload_lds16(W + (size_t)(n0 + row) * DM + k0 + gb * 8, &Bs[s * 8]);
        }
        asm volatile("s_waitcnt vmcnt(0)" ::: "memory");
        __syncthreads();

        #pragma unroll
        for (int kk = 0; kk < 2; ++kk) {
            bf16x8 af[4], bf[4];
            #pragma unroll
            for (int mi = 0; mi < 4; ++mi) {
                const int row = wr * 64 + mi * 16 + cc;
                const int jb  = (kk * 4 + g) ^ (row & 7);
                af[mi] = *(const bf16x8*)&As[(row * 8 + jb) * 8];
            }
            #pragma unroll
            for (int ni = 0; ni < 4; ++ni) {
                const int row = wc * 64 + ni * 16 + cc;
                const int jb  = (kk * 4 + g) ^ (row & 7);
                bf[ni] = *(const bf16x8*)&Bs[(row * 8 + jb) * 8];
            }
            #pragma unroll
            for (int mi = 0; mi < 4; ++mi)
                #pragma unroll
                for (int ni = 0; ni < 4; ++ni)
                    acc[mi][ni] = __builtin_amdgcn_mfma_f32_16x16x32_bf16(af[mi], bf[ni], acc[mi][ni], 0, 0, 0);
        }
    }

    #pragma unroll
    for (int mi = 0; mi < 4; ++mi) {
        #pragma unroll
        for (int r = 0; r < 4; ++r) {
            const int m = m0 + wr * 64 + mi * 16 + 4 * g + r;
            if (MODE == 0) {
                const int b = m >> 11, s = m & 2047;
                #pragma unroll
                for (int ni = 0; ni < 4; ++ni) {
                    const int col = n0 + wc * 64 + ni * 16 + cc;
                    const int h = col >> 6, dh = col & 63;
                    Ob[((size_t)(b * NH + h) * SS + s) * DH + dh] = f2b(acc[mi][ni][r] * oscale);
                }
            } else {
                #pragma unroll
                for (int ni = 0; ni < 4; ++ni) {
                    const int col = n0 + wc * 64 + ni * 16 + cc;
                    outf[(size_t)m * DM + col] = acc[mi][ni][r] + bias[col];
                }
            }
        }
    }
}

// Vb[bh][s][64] bf16 -> Vt[bh][64][S] bf16
__global__ __launch_bounds__(256) void transpose_v(const unsigned short* __restrict__ Vb,
                                                   unsigned short* __restrict__ Vt) {
    __shared__ unsigned short T[64][72];
    const int t  = threadIdx.x;
    const int bh = blockIdx.y;
    const int s0 = blockIdx.x * 64;
    #pragma unroll
    for (int r = 0; r < 2; ++r) {
        const int idx = t + 256 * r;
        const int row = idx >> 3;
        const int d8  = (idx & 7) * 8;
        *(u16x8*)&T[row][d8] = *(const u16x8*)(Vb + ((size_t)bh * SS + s0 + row) * 64 + d8);
    }
    __syncthreads();
    const int d  = t >> 2;
    const int sc = (t & 3) * 16;
    unsigned short tmp[16];
    #pragma unroll
    for (int i = 0; i < 16; ++i) tmp[i] = T[sc + i][d];
    unsigned short* dst = Vt + ((size_t)bh * 64 + d) * SS + s0 + sc;
    *(u16x8*)(dst)     = *(u16x8*)&tmp[0];
    *(u16x8*)(dst + 8) = *(u16x8*)&tmp[8];
}

// MFMA flash attention. Qb,Kb: [BH][S][64] bf16 (Q prescaled 1/8). Vt: [BH][64][S] bf16.
// AOb: [B][S][1024] bf16. Block: 4 waves; wave w owns Q rows q0+w*16..+15. KV tile 64.
__global__ __launch_bounds__(256) void attn_mfma(const unsigned short* __restrict__ Qb,
                                                 const unsigned short* __restrict__ Kb,
                                                 const unsigned short* __restrict__ Vtp,
                                                 unsigned short* __restrict__ AOb) {
    __shared__ unsigned short Ks[64*64];
    __shared__ unsigned short Vs[64*64];
    __shared__ unsigned short Ps[64*64];
    const int t    = threadIdx.x;
    const int lane = t & 63;
    const int w    = t >> 6;
    const int g    = lane >> 4;
    const int cc   = lane & 15;
    const int bh   = blockIdx.y;
    const int q0   = blockIdx.x * 64;

    const unsigned short* Qw = Qb + ((size_t)bh * SS + q0 + w * 16 + cc) * 64;
    const bf16x8 qf0 = *(const bf16x8*)(Qw + 8 * g);
    const bf16x8 qf1 = *(const bf16x8*)(Qw + 32 + 8 * g);

    const unsigned short* Kbase = Kb  + (size_t)bh * SS * 64;
    const unsigned short* Vbase = Vtp + (size_t)bh * 64 * SS;

    const f32x4 zf = {0.f, 0.f, 0.f, 0.f};
    f32x4 oacc[4] = {zf, zf, zf, zf};
    float mrow[4] = {-INFINITY, -INFINITY, -INFINITY, -INFINITY};
    float lrow[4] = {0.f, 0.f, 0.f, 0.f};

    for (int kt = 0; kt < SS / 64; ++kt) {
        __syncthreads();
        #pragma unroll
        for (int r2 = 0; r2 < 2; ++r2) {
            const int idx = t + 256 * r2;
            const int row = idx >> 3;
            const int g8  = idx & 7;
            *(u16x8*)&Ks[row * 64 + ((g8 ^ (row & 7)) << 3)] =
                *(const u16x8*)(Kbase + ((size_t)(kt * 64 + row)) * 64 + g8 * 8);
            *(u16x8*)&Vs[row * 64 + ((g8 ^ (row & 7)) << 3)] =
                *(const u16x8*)(Vbase + (size_t)row * SS + kt * 64 + g8 * 8);
        }
        __syncthreads();

        f32x4 sacc[4] = {zf, zf, zf, zf};
        #pragma unroll
        for (int n = 0; n < 4; ++n) {
            const int key = n * 16 + cc;
            const bf16x8 kf0 = *(const bf16x8*)&Ks[key * 64 + ((g       ^ (key & 7)) << 3)];
            const bf16x8 kf1 = *(const bf16x8*)&Ks[key * 64 + (((4 + g) ^ (key & 7)) << 3)];
            sacc[n] = __builtin_amdgcn_mfma_f32_16x16x32_bf16(qf0, kf0, sacc[n], 0, 0, 0);
            sacc[n] = __builtin_amdgcn_mfma_f32_16x16x32_bf16(qf1, kf1, sacc[n], 0, 0, 0);
        }

        float p[4][4];
        float scl[4];
        #pragma unroll
        for (int r = 0; r < 4; ++r) {
            float mx = fmaxf(fmaxf(sacc[0][r], sacc[1][r]), fmaxf(sacc[2][r], sacc[3][r]));
            mx = fmaxf(mx, __shfl_xor(mx, 1));
            mx = fmaxf(mx, __shfl_xor(mx, 2));
            mx = fmaxf(mx, __shfl_xor(mx, 4));
            mx = fmaxf(mx, __shfl_xor(mx, 8));
            const float nm = fmaxf(mrow[r], mx);
            scl[r] = __expf(mrow[r] - nm);
            mrow[r] = nm;
            float rs = 0.f;
            #pragma unroll
            for (int n = 0; n < 4; ++n) {
                const float pv = __expf(sacc[n][r] - nm);
                p[n][r] = pv;
                rs += pv;
            }
            rs += __shfl_xor(rs, 1);
            rs += __shfl_xor(rs, 2);
            rs += __shfl_xor(rs, 4);
            rs += __shfl_xor(rs, 8);
            lrow[r] = lrow[r] * scl[r] + rs;
        }

        #pragma unroll
        for (int n = 0; n < 4; ++n)
            #pragma unroll
            for (int r = 0; r < 4; ++r) {
                const int qr  = w * 16 + g * 4 + r;
                const int key = n * 16 + cc;
                Ps[qr * 64 + (key ^ ((qr & 7) << 3))] = f2b(p[n][r]);
            }

        #pragma unroll
        for (int n = 0; n < 4; ++n) {
            oacc[n][0] *= scl[0]; oacc[n][1] *= scl[1];
            oacc[n][2] *= scl[2]; oacc[n][3] *= scl[3];
        }

        const int qrow = w * 16 + cc;
        #pragma unroll
        for (int ks = 0; ks < 2; ++ks) {
            const bf16x8 pf = *(const bf16x8*)&Ps[qrow * 64 + (((ks * 4 + g) ^ (qrow & 7)) << 3)];
            #pragma unroll
            for (int n = 0; n < 4; ++n) {
                const int vrow = n * 16 + cc;
                const bf16x8 vf = *(const bf16x8*)&Vs[vrow * 64 + (((ks * 4 + g) ^ (vrow & 7)) << 3)];
                oacc[n] = __builtin_amdgcn_mfma_f32_16x16x32_bf16(pf, vf, oacc[n], 0, 0, 0);
            }
        }
    }

    const int b = bh >> 4, h = bh & 15;
    #pragma unroll
    for (int r = 0; r < 4; ++r) {
        const float inv  = 1.f / lrow[r];
        const int   srow = q0 + w * 16 + g * 4 + r;
        unsigned short* dst = AOb + ((size_t)(b * SS + srow)) * DM + h * 64;
        dst[ 0 + cc] = f2b(oacc[0][r] * inv);
        dst[16 + cc] = f2b(oacc[1][r] * inv);
        dst[32 + cc] = f2b(oacc[2][r] * inv);
        dst[48 + cc] = f2b(oacc[3][r] * inv);
    }
}

extern "C" void kernel_launch(void* const* d_in, const int* in_sizes, int n_in,
                              void* d_out, int out_size, void* d_ws, size_t ws_size,
                              hipStream_t stream) {
    const float* x  = (const float*)d_in[0];
    const float* Wq = (const float*)d_in[1];
    const float* Wk = (const float*)d_in[2];
    const float* Wv = (const float*)d_in[3];
    const float* Wo = (const float*)d_in[4];
    const float* bo = (const float*)d_in[5];
    float* out = (float*)d_out;

    const size_t NEL = (size_t)MROWS * DM;          // 8.4M
    unsigned short* xb  = (unsigned short*)d_ws;    // 16MB bf16 [8192][1024]
    unsigned short* Wb  = xb + NEL;                 // 8MB  bf16 [4][1024][1024]
    unsigned short* Qb  = Wb + (size_t)4 * DM * DM; // 16MB head-major
    unsigned short* Kb  = Qb + NEL;
    unsigned short* Vb  = Kb + NEL;
    unsigned short* Vt  = Vb + NEL;
    unsigned short* AOb = Vt + NEL;                 // 16MB [8192][1024]

    const dim3 blk(256);
    cast_x_kernel<<<dim3(NEL / (256 * 8)), blk, 0, stream>>>(x, xb);
    cast_w_kernel<<<dim3(DM * DM / (256 * 8), 4), blk, 0, stream>>>(Wq, Wk, Wv, Wo, Wb);

    gemm_mfma<0><<<dim3(MROWS / 128, DM / 128, 3), blk, 0, stream>>>(
        xb, Wb, Wb + (size_t)DM * DM, Wb + (size_t)2 * DM * DM,
        Qb, Kb, Vb, nullptr, nullptr);

    transpose_v<<<dim3(SS / 64, BB * NH), blk, 0, stream>>>(Vb, Vt);
    attn_mfma<<<dim3(SS / 64, BB * NH), blk, 0, stream>>>(Qb, Kb, Vt, AOb);

    gemm_mfma<1><<<dim3(MROWS / 128, DM / 128, 1), blk, 0, stream>>>(
        AOb, Wb + (size_t)3 * DM * DM, nullptr, nullptr,
        nullptr, nullptr, nullptr, out, bo);
}

// Round 10
// 384.420 us; speedup vs baseline: 5.8504x; 1.0344x over previous
//
#include <hip/hip_runtime.h>
#include <hip/hip_bf16.h>
#include <math.h>

#define BB 4
#define SS 2048
#define DM 1024
#define NH 16
#define DH 64
#define MROWS (BB*SS)
#define NT (SS/64)

typedef __attribute__((ext_vector_type(8))) short bf16x8;
typedef __attribute__((ext_vector_type(4))) float f32x4;
typedef __attribute__((ext_vector_type(8))) unsigned short u16x8;

__device__ __forceinline__ unsigned short f2b(float f) {
    __hip_bfloat16 b = __float2bfloat16(f);
    return *reinterpret_cast<unsigned short*>(&b);
}

__device__ __forceinline__ float fexp2(float x) {
    float r;
    asm("v_exp_f32 %0, %1" : "=v"(r) : "v"(x));
    return r;
}

__device__ __forceinline__ void gload_lds16(const void* g, void* l) {
    __builtin_amdgcn_global_load_lds((const __attribute__((address_space(1))) unsigned int*)g,
                                     (__attribute__((address_space(3))) unsigned int*)l,
                                     16, 0, 0);
}

// ---------------- casts ----------------
__global__ __launch_bounds__(256) void cast_x_kernel(const float* __restrict__ in,
                                                     unsigned short* __restrict__ out) {
    const size_t i = ((size_t)blockIdx.x * 256 + threadIdx.x) * 8;
    const float4 a = *(const float4*)(in + i);
    const float4 b = *(const float4*)(in + i + 4);
    unsigned short pk[8] = {f2b(a.x), f2b(a.y), f2b(a.z), f2b(a.w),
                            f2b(b.x), f2b(b.y), f2b(b.z), f2b(b.w)};
    *(u16x8*)(out + i) = *(u16x8*)pk;
}

__global__ __launch_bounds__(256) void cast_w_kernel(const float* __restrict__ Wq,
                                                     const float* __restrict__ Wk,
                                                     const float* __restrict__ Wv,
                                                     const float* __restrict__ Wo,
                                                     unsigned short* __restrict__ out) {
    const float* src = (blockIdx.y == 0) ? Wq : (blockIdx.y == 1) ? Wk
                     : (blockIdx.y == 2) ? Wv : Wo;
    const size_t i = ((size_t)blockIdx.x * 256 + threadIdx.x) * 8;
    const float4 a = *(const float4*)(src + i);
    const float4 b = *(const float4*)(src + i + 4);
    unsigned short pk[8] = {f2b(a.x), f2b(a.y), f2b(a.z), f2b(a.w),
                            f2b(b.x), f2b(b.y), f2b(b.z), f2b(b.w)};
    *(u16x8*)(out + (size_t)blockIdx.y * DM * DM + i) = *(u16x8*)pk;
}

// ---------------- bf16 MFMA GEMM: C[m][n] = sum_k A[m][k] * W[n][k] ----------------
// (unchanged from the passing Round-3 kernel)
template<int MODE>
__global__ __launch_bounds__(256) void gemm_mfma(const unsigned short* __restrict__ A,
                                                 const unsigned short* __restrict__ Wq,
                                                 const unsigned short* __restrict__ Wk,
                                                 const unsigned short* __restrict__ Wv,
                                                 unsigned short* __restrict__ Oq,
                                                 unsigned short* __restrict__ Ok,
                                                 unsigned short* __restrict__ Ov,
                                                 float* __restrict__ outf,
                                                 const float* __restrict__ bias) {
    __shared__ __align__(16) unsigned short As[128 * 64];
    __shared__ __align__(16) unsigned short Bs[128 * 64];
    const int t  = threadIdx.x;
    const int l  = t & 63;
    const int w  = t >> 6;
    const int g  = l >> 4;
    const int cc = l & 15;
    const int wr = w >> 1, wc = w & 1;
    const int m0 = blockIdx.x * 128;
    const int n0 = blockIdx.y * 128;

    const unsigned short* W;
    unsigned short* Ob = nullptr;
    float oscale = 1.f;
    if (MODE == 0) {
        const int z = blockIdx.z;
        W  = (z == 0) ? Wq : (z == 1) ? Wk : Wv;
        Ob = (z == 0) ? Oq : (z == 1) ? Ok : Ov;
        if (z == 0) oscale = 0.18033688011112042f;  // (1/8)*log2(e): softmax runs in base-2
    } else {
        W = Wq;
    }

    const f32x4 zf = {0.f, 0.f, 0.f, 0.f};
    f32x4 acc[4][4] = {{zf,zf,zf,zf},{zf,zf,zf,zf},{zf,zf,zf,zf},{zf,zf,zf,zf}};

    for (int k0 = 0; k0 < DM; k0 += 64) {
        __syncthreads();
        #pragma unroll
        for (int i = 0; i < 4; ++i) {
            const int s   = i * 256 + t;
            const int row = s >> 3;
            const int j   = s & 7;
            const int gb  = j ^ (row & 7);
            gload_lds16(A + (size_t)(m0 + row) * DM + k0 + gb * 8, &As[s * 8]);
            gload_lds16(W + (size_t)(n0 + row) * DM + k0 + gb * 8, &Bs[s * 8]);
        }
        asm volatile("s_waitcnt vmcnt(0)" ::: "memory");
        __syncthreads();

        #pragma unroll
        for (int kk = 0; kk < 2; ++kk) {
            bf16x8 af[4], bf[4];
            #pragma unroll
            for (int mi = 0; mi < 4; ++mi) {
                const int row = wr * 64 + mi * 16 + cc;
                const int jb  = (kk * 4 + g) ^ (row & 7);
                af[mi] = *(const bf16x8*)&As[(row * 8 + jb) * 8];
            }
            #pragma unroll
            for (int ni = 0; ni < 4; ++ni) {
                const int row = wc * 64 + ni * 16 + cc;
                const int jb  = (kk * 4 + g) ^ (row & 7);
                bf[ni] = *(const bf16x8*)&Bs[(row * 8 + jb) * 8];
            }
            #pragma unroll
            for (int mi = 0; mi < 4; ++mi)
                #pragma unroll
                for (int ni = 0; ni < 4; ++ni)
                    acc[mi][ni] = __builtin_amdgcn_mfma_f32_16x16x32_bf16(af[mi], bf[ni], acc[mi][ni], 0, 0, 0);
        }
    }

    #pragma unroll
    for (int mi = 0; mi < 4; ++mi) {
        #pragma unroll
        for (int r = 0; r < 4; ++r) {
            const int m = m0 + wr * 64 + mi * 16 + 4 * g + r;
            if (MODE == 0) {
                const int b = m >> 11, s = m & 2047;
                #pragma unroll
                for (int ni = 0; ni < 4; ++ni) {
                    const int col = n0 + wc * 64 + ni * 16 + cc;
                    const int h = col >> 6, dh = col & 63;
                    Ob[((size_t)(b * NH + h) * SS + s) * DH + dh] = f2b(acc[mi][ni][r] * oscale);
                }
            } else {
                #pragma unroll
                for (int ni = 0; ni < 4; ++ni) {
                    const int col = n0 + wc * 64 + ni * 16 + cc;
                    outf[(size_t)m * DM + col] = acc[mi][ni][r] + bias[col];
                }
            }
        }
    }
}

// Vb[bh][s][64] bf16 -> Vt[bh][64][S] bf16
__global__ __launch_bounds__(256) void transpose_v(const unsigned short* __restrict__ Vb,
                                                   unsigned short* __restrict__ Vt) {
    __shared__ unsigned short T[64][72];
    const int t  = threadIdx.x;
    const int bh = blockIdx.y;
    const int s0 = blockIdx.x * 64;
    #pragma unroll
    for (int r = 0; r < 2; ++r) {
        const int idx = t + 256 * r;
        const int row = idx >> 3;
        const int d8  = (idx & 7) * 8;
        *(u16x8*)&T[row][d8] = *(const u16x8*)(Vb + ((size_t)bh * SS + s0 + row) * 64 + d8);
    }
    __syncthreads();
    const int d  = t >> 2;
    const int sc = (t & 3) * 16;
    unsigned short tmp[16];
    #pragma unroll
    for (int i = 0; i < 16; ++i) tmp[i] = T[sc + i][d];
    unsigned short* dst = Vt + ((size_t)bh * 64 + d) * SS + s0 + sc;
    *(u16x8*)(dst)     = *(u16x8*)&tmp[0];
    *(u16x8*)(dst + 8) = *(u16x8*)&tmp[8];
}

// MFMA flash attention, async double-buffered staging.
// Qb,Kb: [BH][S][64] bf16 (Q prescaled by log2e/8 => base-2 softmax). Vt: [BH][64][S] bf16.
// AOb: [B][S][1024] bf16. 4 waves; wave w owns Q rows q0+w*16..+15. KV tile 64.
__global__ __launch_bounds__(256) void attn_mfma(const unsigned short* __restrict__ Qb,
                                                 const unsigned short* __restrict__ Kb,
                                                 const unsigned short* __restrict__ Vtp,
                                                 unsigned short* __restrict__ AOb) {
    __shared__ __align__(16) unsigned short Ks[2][64*64];  // [key][dh], dh-blocks XOR-swizzled by key&7
    __shared__ __align__(16) unsigned short Vs[2][64*64];  // [dh][key], key-blocks XOR-swizzled by dh&7
    __shared__ unsigned short Ps[64*64];
    const int t    = threadIdx.x;
    const int lane = t & 63;
    const int w    = t >> 6;
    const int g    = lane >> 4;
    const int cc   = lane & 15;
    const int bh   = blockIdx.y;
    const int q0   = blockIdx.x * 64;

    const unsigned short* Qw = Qb + ((size_t)bh * SS + q0 + w * 16 + cc) * 64;
    const bf16x8 qf0 = *(const bf16x8*)(Qw + 8 * g);
    const bf16x8 qf1 = *(const bf16x8*)(Qw + 32 + 8 * g);

    const unsigned short* Kbase = Kb  + (size_t)bh * SS * 64;
    const unsigned short* Vbase = Vtp + (size_t)bh * 64 * SS;

    // Stage tile kt into buffer buf: lane-linear LDS dest (gload_lds requirement),
    // swizzle applied by pre-swizzling the GLOBAL source (same involution readers use).
    auto stage = [&](int buf, int kt) {
        #pragma unroll
        for (int r2 = 0; r2 < 2; ++r2) {
            const int idx = r2 * 256 + t;
            const int row = idx >> 3;
            const int gb  = (idx & 7) ^ (row & 7);
            gload_lds16(Kbase + (size_t)(kt * 64 + row) * 64 + gb * 8, &Ks[buf][idx * 8]);
            gload_lds16(Vbase + (size_t)row * SS + kt * 64 + gb * 8, &Vs[buf][idx * 8]);
        }
    };

    // Drain Q loads so vmcnt counts only staging DMAs from here on.
    asm volatile("s_waitcnt vmcnt(0)" ::: "memory");
    stage(0, 0);  // 4 loads in flight

    const f32x4 zf = {0.f, 0.f, 0.f, 0.f};
    f32x4 oacc[4] = {zf, zf, zf, zf};
    float mrow[4] = {-INFINITY, -INFINITY, -INFINITY, -INFINITY};
    float lrow[4] = {0.f, 0.f, 0.f, 0.f};

    for (int kt = 0; kt < NT; ++kt) {
        const int cur = kt & 1;
        if (kt + 1 < NT) {
            stage(cur ^ 1, kt + 1);                       // prefetch next tile (8 in flight)
            asm volatile("s_waitcnt vmcnt(4)" ::: "memory");  // current tile landed
        } else {
            asm volatile("s_waitcnt vmcnt(0)" ::: "memory");
        }
        __syncthreads();

        // S' = (Q*log2e/8) K^T : D row = 4*g+r, col = n*16+cc
        f32x4 sacc[4] = {zf, zf, zf, zf};
        __builtin_amdgcn_s_setprio(1);
        #pragma unroll
        for (int n = 0; n < 4; ++n) {
            const int key = n * 16 + cc;
            const bf16x8 kf0 = *(const bf16x8*)&Ks[cur][key * 64 + ((g       ^ (key & 7)) << 3)];
            const bf16x8 kf1 = *(const bf16x8*)&Ks[cur][key * 64 + (((4 + g) ^ (key & 7)) << 3)];
            sacc[n] = __builtin_amdgcn_mfma_f32_16x16x32_bf16(qf0, kf0, sacc[n], 0, 0, 0);
            sacc[n] = __builtin_amdgcn_mfma_f32_16x16x32_bf16(qf1, kf1, sacc[n], 0, 0, 0);
        }
        __builtin_amdgcn_s_setprio(0);

        // base-2 online softmax
        float p[4][4];
        float scl[4];
        #pragma unroll
        for (int r = 0; r < 4; ++r) {
            float mx = fmaxf(fmaxf(sacc[0][r], sacc[1][r]), fmaxf(sacc[2][r], sacc[3][r]));
            mx = fmaxf(mx, __shfl_xor(mx, 1));
            mx = fmaxf(mx, __shfl_xor(mx, 2));
            mx = fmaxf(mx, __shfl_xor(mx, 4));
            mx = fmaxf(mx, __shfl_xor(mx, 8));
            const float nm = fmaxf(mrow[r], mx);
            scl[r] = fexp2(mrow[r] - nm);
            mrow[r] = nm;
            float rs = 0.f;
            #pragma unroll
            for (int n = 0; n < 4; ++n) {
                const float pv = fexp2(sacc[n][r] - nm);
                p[n][r] = pv;
                rs += pv;
            }
            rs += __shfl_xor(rs, 1);
            rs += __shfl_xor(rs, 2);
            rs += __shfl_xor(rs, 4);
            rs += __shfl_xor(rs, 8);
            lrow[r] = lrow[r] * scl[r] + rs;
        }

        // P -> LDS bf16 (wave-private rows; no barrier needed)
        #pragma unroll
        for (int n = 0; n < 4; ++n)
            #pragma unroll
            for (int r = 0; r < 4; ++r) {
                const int qr  = w * 16 + g * 4 + r;
                const int key = n * 16 + cc;
                Ps[qr * 64 + (key ^ ((qr & 7) << 3))] = f2b(p[n][r]);
            }

        #pragma unroll
        for (int n = 0; n < 4; ++n) {
            oacc[n][0] *= scl[0]; oacc[n][1] *= scl[1];
            oacc[n][2] *= scl[2]; oacc[n][3] *= scl[3];
        }

        // O += P V
        const int qrow = w * 16 + cc;
        __builtin_amdgcn_s_setprio(1);
        #pragma unroll
        for (int ks = 0; ks < 2; ++ks) {
            const bf16x8 pf = *(const bf16x8*)&Ps[qrow * 64 + (((ks * 4 + g) ^ (qrow & 7)) << 3)];
            #pragma unroll
            for (int n = 0; n < 4; ++n) {
                const int vrow = n * 16 + cc;
                const bf16x8 vf = *(const bf16x8*)&Vs[cur][vrow * 64 + (((ks * 4 + g) ^ (vrow & 7)) << 3)];
                oacc[n] = __builtin_amdgcn_mfma_f32_16x16x32_bf16(pf, vf, oacc[n], 0, 0, 0);
            }
        }
        __builtin_amdgcn_s_setprio(0);

        __syncthreads();   // all waves done reading buf[cur] before it is re-staged
    }

    const int b = bh >> 4, h = bh & 15;
    #pragma unroll
    for (int r = 0; r < 4; ++r) {
        const float inv  = 1.f / lrow[r];
        const int   srow = q0 + w * 16 + g * 4 + r;
        unsigned short* dst = AOb + ((size_t)(b * SS + srow)) * DM + h * 64;
        dst[ 0 + cc] = f2b(oacc[0][r] * inv);
        dst[16 + cc] = f2b(oacc[1][r] * inv);
        dst[32 + cc] = f2b(oacc[2][r] * inv);
        dst[48 + cc] = f2b(oacc[3][r] * inv);
    }
}

extern "C" void kernel_launch(void* const* d_in, const int* in_sizes, int n_in,
                              void* d_out, int out_size, void* d_ws, size_t ws_size,
                              hipStream_t stream) {
    const float* x  = (const float*)d_in[0];
    const float* Wq = (const float*)d_in[1];
    const float* Wk = (const float*)d_in[2];
    const float* Wv = (const float*)d_in[3];
    const float* Wo = (const float*)d_in[4];
    const float* bo = (const float*)d_in[5];
    float* out = (float*)d_out;

    const size_t NEL = (size_t)MROWS * DM;          // 8.4M
    unsigned short* xb  = (unsigned short*)d_ws;    // 16MB bf16 [8192][1024]
    unsigned short* Wb  = xb + NEL;                 // 8MB  bf16 [4][1024][1024]
    unsigned short* Qb  = Wb + (size_t)4 * DM * DM; // 16MB head-major
    unsigned short* Kb  = Qb + NEL;
    unsigned short* Vb  = Kb + NEL;
    unsigned short* Vt  = Vb + NEL;
    unsigned short* AOb = Vt + NEL;                 // 16MB [8192][1024]

    const dim3 blk(256);
    cast_x_kernel<<<dim3(NEL / (256 * 8)), blk, 0, stream>>>(x, xb);
    cast_w_kernel<<<dim3(DM * DM / (256 * 8), 4), blk, 0, stream>>>(Wq, Wk, Wv, Wo, Wb);

    gemm_mfma<0><<<dim3(MROWS / 128, DM / 128, 3), blk, 0, stream>>>(
        xb, Wb, Wb + (size_t)DM * DM, Wb + (size_t)2 * DM * DM,
        Qb, Kb, Vb, nullptr, nullptr);

    transpose_v<<<dim3(SS / 64, BB * NH), blk, 0, stream>>>(Vb, Vt);
    attn_mfma<<<dim3(SS / 64, BB * NH), blk, 0, stream>>>(Qb, Kb, Vt, AOb);

    gemm_mfma<1><<<dim3(MROWS / 128, DM / 128, 1), blk, 0, stream>>>(
        AOb, Wb + (size_t)3 * DM * DM, nullptr, nullptr,
        nullptr, nullptr, nullptr, out, bo);
}

// Round 15
// 321.018 us; speedup vs baseline: 7.0058x; 1.1975x over previous
//
#include <hip/hip_runtime.h>
#include <hip/hip_bf16.h>
#include <math.h>

#define BB 4
#define SS 2048
#define DM 1024
#define NH 16
#define DH 64
#define MROWS (BB*SS)
#define NT (SS/64)

typedef __attribute__((ext_vector_type(8))) short bf16x8;
typedef __attribute__((ext_vector_type(4))) float f32x4;
typedef __attribute__((ext_vector_type(8))) unsigned short u16x8;
typedef __attribute__((ext_vector_type(4))) unsigned short u16x4;

__device__ __forceinline__ unsigned short f2b(float f) {
    __hip_bfloat16 b = __float2bfloat16(f);
    return *reinterpret_cast<unsigned short*>(&b);
}

__device__ __forceinline__ float fexp2(float x) {
    float r;
    asm("v_exp_f32 %0, %1" : "=v"(r) : "v"(x));
    return r;
}

__device__ __forceinline__ void gload_lds16(const void* g, void* l) {
    __builtin_amdgcn_global_load_lds((const __attribute__((address_space(1))) unsigned int*)g,
                                     (__attribute__((address_space(3))) unsigned int*)l,
                                     16, 0, 0);
}

// ---------------- casts ----------------
__global__ __launch_bounds__(256) void cast_x_kernel(const float* __restrict__ in,
                                                     unsigned short* __restrict__ out) {
    const size_t i = ((size_t)blockIdx.x * 256 + threadIdx.x) * 8;
    const float4 a = *(const float4*)(in + i);
    const float4 b = *(const float4*)(in + i + 4);
    unsigned short pk[8] = {f2b(a.x), f2b(a.y), f2b(a.z), f2b(a.w),
                            f2b(b.x), f2b(b.y), f2b(b.z), f2b(b.w)};
    *(u16x8*)(out + i) = *(u16x8*)pk;
}

__global__ __launch_bounds__(256) void cast_w_kernel(const float* __restrict__ Wq,
                                                     const float* __restrict__ Wk,
                                                     const float* __restrict__ Wv,
                                                     const float* __restrict__ Wo,
                                                     unsigned short* __restrict__ out) {
    const float* src = (blockIdx.y == 0) ? Wq : (blockIdx.y == 1) ? Wk
                     : (blockIdx.y == 2) ? Wv : Wo;
    const size_t i = ((size_t)blockIdx.x * 256 + threadIdx.x) * 8;
    const float4 a = *(const float4*)(src + i);
    const float4 b = *(const float4*)(src + i + 4);
    unsigned short pk[8] = {f2b(a.x), f2b(a.y), f2b(a.z), f2b(a.w),
                            f2b(b.x), f2b(b.y), f2b(b.z), f2b(b.w)};
    *(u16x8*)(out + (size_t)blockIdx.y * DM * DM + i) = *(u16x8*)pk;
}

// ---------------- bf16 MFMA GEMM (unchanged, passing) ----------------
template<int MODE>
__global__ __launch_bounds__(256) void gemm_mfma(const unsigned short* __restrict__ A,
                                                 const unsigned short* __restrict__ Wq,
                                                 const unsigned short* __restrict__ Wk,
                                                 const unsigned short* __restrict__ Wv,
                                                 unsigned short* __restrict__ Oq,
                                                 unsigned short* __restrict__ Ok,
                                                 unsigned short* __restrict__ Ov,
                                                 float* __restrict__ outf,
                                                 const float* __restrict__ bias) {
    __shared__ __align__(16) unsigned short As[128 * 64];
    __shared__ __align__(16) unsigned short Bs[128 * 64];
    const int t  = threadIdx.x;
    const int l  = t & 63;
    const int w  = t >> 6;
    const int g  = l >> 4;
    const int cc = l & 15;
    const int wr = w >> 1, wc = w & 1;
    const int m0 = blockIdx.x * 128;
    const int n0 = blockIdx.y * 128;

    const unsigned short* W;
    unsigned short* Ob = nullptr;
    float oscale = 1.f;
    if (MODE == 0) {
        const int z = blockIdx.z;
        W  = (z == 0) ? Wq : (z == 1) ? Wk : Wv;
        Ob = (z == 0) ? Oq : (z == 1) ? Ok : Ov;
        if (z == 0) oscale = 0.18033688011112042f;  // (1/8)*log2(e): softmax runs in base-2
    } else {
        W = Wq;
    }

    const f32x4 zf = {0.f, 0.f, 0.f, 0.f};
    f32x4 acc[4][4] = {{zf,zf,zf,zf},{zf,zf,zf,zf},{zf,zf,zf,zf},{zf,zf,zf,zf}};

    for (int k0 = 0; k0 < DM; k0 += 64) {
        __syncthreads();
        #pragma unroll
        for (int i = 0; i < 4; ++i) {
            const int s   = i * 256 + t;
            const int row = s >> 3;
            const int j   = s & 7;
            const int gb  = j ^ (row & 7);
            gload_lds16(A + (size_t)(m0 + row) * DM + k0 + gb * 8, &As[s * 8]);
            gload_lds16(W + (size_t)(n0 + row) * DM + k0 + gb * 8, &Bs[s * 8]);
        }
        asm volatile("s_waitcnt vmcnt(0)" ::: "memory");
        __syncthreads();

        #pragma unroll
        for (int kk = 0; kk < 2; ++kk) {
            bf16x8 af[4], bf[4];
            #pragma unroll
            for (int mi = 0; mi < 4; ++mi) {
                const int row = wr * 64 + mi * 16 + cc;
                const int jb  = (kk * 4 + g) ^ (row & 7);
                af[mi] = *(const bf16x8*)&As[(row * 8 + jb) * 8];
            }
            #pragma unroll
            for (int ni = 0; ni < 4; ++ni) {
                const int row = wc * 64 + ni * 16 + cc;
                const int jb  = (kk * 4 + g) ^ (row & 7);
                bf[ni] = *(const bf16x8*)&Bs[(row * 8 + jb) * 8];
            }
            #pragma unroll
            for (int mi = 0; mi < 4; ++mi)
                #pragma unroll
                for (int ni = 0; ni < 4; ++ni)
                    acc[mi][ni] = __builtin_amdgcn_mfma_f32_16x16x32_bf16(af[mi], bf[ni], acc[mi][ni], 0, 0, 0);
        }
    }

    #pragma unroll
    for (int mi = 0; mi < 4; ++mi) {
        #pragma unroll
        for (int r = 0; r < 4; ++r) {
            const int m = m0 + wr * 64 + mi * 16 + 4 * g + r;
            if (MODE == 0) {
                const int b = m >> 11, s = m & 2047;
                #pragma unroll
                for (int ni = 0; ni < 4; ++ni) {
                    const int col = n0 + wc * 64 + ni * 16 + cc;
                    const int h = col >> 6, dh = col & 63;
                    Ob[((size_t)(b * NH + h) * SS + s) * DH + dh] = f2b(acc[mi][ni][r] * oscale);
                }
            } else {
                #pragma unroll
                for (int ni = 0; ni < 4; ++ni) {
                    const int col = n0 + wc * 64 + ni * 16 + cc;
                    outf[(size_t)m * DM + col] = acc[mi][ni][r] + bias[col];
                }
            }
        }
    }
}

// Vb[bh][s][64] bf16 -> Vt[bh][64][S] bf16
__global__ __launch_bounds__(256) void transpose_v(const unsigned short* __restrict__ Vb,
                                                   unsigned short* __restrict__ Vt) {
    __shared__ unsigned short T[64][72];
    const int t  = threadIdx.x;
    const int bh = blockIdx.y;
    const int s0 = blockIdx.x * 64;
    #pragma unroll
    for (int r = 0; r < 2; ++r) {
        const int idx = t + 256 * r;
        const int row = idx >> 3;
        const int d8  = (idx & 7) * 8;
        *(u16x8*)&T[row][d8] = *(const u16x8*)(Vb + ((size_t)bh * SS + s0 + row) * 64 + d8);
    }
    __syncthreads();
    const int d  = t >> 2;
    const int sc = (t & 3) * 16;
    unsigned short tmp[16];
    #pragma unroll
    for (int i = 0; i < 16; ++i) tmp[i] = T[sc + i][d];
    unsigned short* dst = Vt + ((size_t)bh * 64 + d) * SS + s0 + sc;
    *(u16x8*)(dst)     = *(u16x8*)&tmp[0];
    *(u16x8*)(dst + 8) = *(u16x8*)&tmp[8];
}

// MFMA flash attention, swapped-operand form: per lane ONE q-row.
// QK^T: mfma(K, Q) -> S^T[key=16n+4g+r][q=16w+cc]. Softmax reduce = 15 in-lane + 2 shfl.
// PV:   mfma(Vt, P^T) -> O^T[dh=16n2+4g+r][q=16w+cc].
// Fragment reads are byte-identical to the previously passing kernel (A/B layouts coincide).
__global__ __launch_bounds__(256) void attn_mfma(const unsigned short* __restrict__ Qb,
                                                 const unsigned short* __restrict__ Kb,
                                                 const unsigned short* __restrict__ Vtp,
                                                 unsigned short* __restrict__ AOb) {
    __shared__ __align__(16) unsigned short Ks[2][64*64];  // [key][dh-blocks], XOR-swz by key&7
    __shared__ __align__(16) unsigned short Vs[2][64*64];  // [dh][key-blocks], XOR-swz by dh&7
    __shared__ __align__(16) unsigned short Ps[4][16*64];  // per-wave [q=cc][key], 8B-unit XOR-swz
    const int t    = threadIdx.x;
    const int lane = t & 63;
    const int w    = t >> 6;
    const int g    = lane >> 4;
    const int cc   = lane & 15;
    const int c7   = cc & 7;
    const int bh   = blockIdx.y;
    const int q0   = blockIdx.x * 64;

    const unsigned short* Qw = Qb + ((size_t)bh * SS + q0 + w * 16 + cc) * 64;
    const bf16x8 qf0 = *(const bf16x8*)(Qw + 8 * g);
    const bf16x8 qf1 = *(const bf16x8*)(Qw + 32 + 8 * g);

    const unsigned short* Kbase = Kb  + (size_t)bh * SS * 64;
    const unsigned short* Vbase = Vtp + (size_t)bh * 64 * SS;

    auto stage = [&](int buf, int kt) {
        #pragma unroll
        for (int r2 = 0; r2 < 2; ++r2) {
            const int idx = r2 * 256 + t;
            const int row = idx >> 3;
            const int gb  = (idx & 7) ^ (row & 7);
            gload_lds16(Kbase + (size_t)(kt * 64 + row) * 64 + gb * 8, &Ks[buf][idx * 8]);
            gload_lds16(Vbase + (size_t)row * SS + kt * 64 + gb * 8, &Vs[buf][idx * 8]);
        }
    };

    asm volatile("s_waitcnt vmcnt(0)" ::: "memory");  // drain Q loads
    stage(0, 0);

    const f32x4 zf = {0.f, 0.f, 0.f, 0.f};
    f32x4 oacc[4] = {zf, zf, zf, zf};
    float mrow = -INFINITY;
    float lrow = 0.f;
    unsigned short* Pw = &Ps[w][0];

    for (int kt = 0; kt < NT; ++kt) {
        const int cur = kt & 1;
        if (kt + 1 < NT) {
            stage(cur ^ 1, kt + 1);
            asm volatile("s_waitcnt vmcnt(4)" ::: "memory");
        } else {
            asm volatile("s_waitcnt vmcnt(0)" ::: "memory");
        }
        __syncthreads();

        // S^T = K (Q*log2e/8)^T : lane holds keys {16n+4g+r}, q = 16w+cc
        f32x4 sacc[4] = {zf, zf, zf, zf};
        __builtin_amdgcn_s_setprio(1);
        #pragma unroll
        for (int n = 0; n < 4; ++n) {
            const int key = n * 16 + cc;
            const bf16x8 kf0 = *(const bf16x8*)&Ks[cur][key * 64 + ((g       ^ (key & 7)) << 3)];
            const bf16x8 kf1 = *(const bf16x8*)&Ks[cur][key * 64 + (((4 + g) ^ (key & 7)) << 3)];
            sacc[n] = __builtin_amdgcn_mfma_f32_16x16x32_bf16(kf0, qf0, sacc[n], 0, 0, 0);
            sacc[n] = __builtin_amdgcn_mfma_f32_16x16x32_bf16(kf1, qf1, sacc[n], 0, 0, 0);
        }
        __builtin_amdgcn_s_setprio(0);

        // base-2 online softmax for the lane's single q-row
        float mx = fmaxf(fmaxf(sacc[0][0], sacc[0][1]), fmaxf(sacc[0][2], sacc[0][3]));
        #pragma unroll
        for (int n = 1; n < 4; ++n)
            mx = fmaxf(mx, fmaxf(fmaxf(sacc[n][0], sacc[n][1]), fmaxf(sacc[n][2], sacc[n][3])));
        mx = fmaxf(mx, __shfl_xor(mx, 16));
        mx = fmaxf(mx, __shfl_xor(mx, 32));
        const float nm  = fmaxf(mrow, mx);
        const float scl = fexp2(mrow - nm);
        mrow = nm;

        float p[4][4];
        float rs = 0.f;
        #pragma unroll
        for (int n = 0; n < 4; ++n) {
            #pragma unroll
            for (int r = 0; r < 4; ++r) {
                const float pv = fexp2(sacc[n][r] - nm);
                p[n][r] = pv;
                rs += pv;
            }
        }
        rs += __shfl_xor(rs, 16);
        rs += __shfl_xor(rs, 32);
        lrow = lrow * scl + rs;

        // P^T -> wave-private LDS: keys 16n+4g+{0..3} contiguous -> packed 8B writes
        #pragma unroll
        for (int n = 0; n < 4; ++n) {
            u16x4 pk = {f2b(p[n][0]), f2b(p[n][1]), f2b(p[n][2]), f2b(p[n][3])};
            *(u16x4*)&Pw[cc * 64 + (((4 * n + g) ^ (2 * c7)) << 2)] = pk;
        }

        #pragma unroll
        for (int n2 = 0; n2 < 4; ++n2) {
            oacc[n2][0] *= scl; oacc[n2][1] *= scl;
            oacc[n2][2] *= scl; oacc[n2][3] *= scl;
        }

        // O^T += Vt P^T : A = V^T[dh][key], B = P^T[key][q]
        __builtin_amdgcn_s_setprio(1);
        #pragma unroll
        for (int ks = 0; ks < 2; ++ks) {
            const bf16x8 pf = *(const bf16x8*)&Pw[cc * 64 + (((8 * ks + 2 * g) ^ (2 * c7)) << 2)];
            #pragma unroll
            for (int n2 = 0; n2 < 4; ++n2) {
                const int vrow = n2 * 16 + cc;
                const bf16x8 vf = *(const bf16x8*)&Vs[cur][vrow * 64 + (((ks * 4 + g) ^ (vrow & 7)) << 3)];
                oacc[n2] = __builtin_amdgcn_mfma_f32_16x16x32_bf16(vf, pf, oacc[n2], 0, 0, 0);
            }
        }
        __builtin_amdgcn_s_setprio(0);

        __syncthreads();   // all waves done reading buf[cur] before restage
    }

    // lane owns q-row 16w+cc: dh = 16n2+4g+r, packed 8B stores
    const int b = bh >> 4, h = bh & 15;
    const float inv = 1.f / lrow;
    unsigned short* dst = AOb + ((size_t)(b * SS + q0 + w * 16 + cc)) * DM + h * 64;
    #pragma unroll
    for (int n2 = 0; n2 < 4; ++n2) {
        u16x4 o = {f2b(oacc[n2][0] * inv), f2b(oacc[n2][1] * inv),
                   f2b(oacc[n2][2] * inv), f2b(oacc[n2][3] * inv)};
        *(u16x4*)(dst + n2 * 16 + 4 * g) = o;
    }
}

extern "C" void kernel_launch(void* const* d_in, const int* in_sizes, int n_in,
                              void* d_out, int out_size, void* d_ws, size_t ws_size,
                              hipStream_t stream) {
    const float* x  = (const float*)d_in[0];
    const float* Wq = (const float*)d_in[1];
    const float* Wk = (const float*)d_in[2];
    const float* Wv = (const float*)d_in[3];
    const float* Wo = (const float*)d_in[4];
    const float* bo = (const float*)d_in[5];
    float* out = (float*)d_out;

    const size_t NEL = (size_t)MROWS * DM;          // 8.4M
    unsigned short* xb  = (unsigned short*)d_ws;    // 16MB bf16 [8192][1024]
    unsigned short* Wb  = xb + NEL;                 // 8MB  bf16 [4][1024][1024]
    unsigned short* Qb  = Wb + (size_t)4 * DM * DM; // 16MB head-major
    unsigned short* Kb  = Qb + NEL;
    unsigned short* Vb  = Kb + NEL;
    unsigned short* Vt  = Vb + NEL;
    unsigned short* AOb = Vt + NEL;                 // 16MB [8192][1024]

    const dim3 blk(256);
    cast_x_kernel<<<dim3(NEL / (256 * 8)), blk, 0, stream>>>(x, xb);
    cast_w_kernel<<<dim3(DM * DM / (256 * 8), 4), blk, 0, stream>>>(Wq, Wk, Wv, Wo, Wb);

    gemm_mfma<0><<<dim3(MROWS / 128, DM / 128, 3), blk, 0, stream>>>(
        xb, Wb, Wb + (size_t)DM * DM, Wb + (size_t)2 * DM * DM,
        Qb, Kb, Vb, nullptr, nullptr);

    transpose_v<<<dim3(SS / 64, BB * NH), blk, 0, stream>>>(Vb, Vt);
    attn_mfma<<<dim3(SS / 64, BB * NH), blk, 0, stream>>>(Qb, Kb, Vt, AOb);

    gemm_mfma<1><<<dim3(MROWS / 128, DM / 128, 1), blk, 0, stream>>>(
        AOb, Wb + (size_t)3 * DM * DM, nullptr, nullptr,
        nullptr, nullptr, nullptr, out, bo);
}